// Round 6
// baseline (507.752 us; speedup 1.0000x reference)
//
#include <hip/hip_runtime.h>
#include <hip/hip_bf16.h>

#define N_ROWS 8192
#define D_DIM  256

typedef __attribute__((ext_vector_type(8))) short bf16x8;
typedef __attribute__((ext_vector_type(4))) float f32x4;

__device__ __forceinline__ unsigned short f2bf(float x) {
    unsigned u = __float_as_uint(x);
    u = (u + 0x7FFFu + ((u >> 16) & 1u)) >> 16;
    return (unsigned short)u;
}
__device__ __forceinline__ float bf2f(unsigned short u) {
    return __uint_as_float(((unsigned)u) << 16);
}
__device__ __forceinline__ f32x4 mfma16(bf16x8 a, bf16x8 b, f32x4 c) {
    return __builtin_amdgcn_mfma_f32_16x16x32_bf16(a, b, c, 0, 0, 0);
}

// ---------------------------------------------------------------------------
// Kernel 0: prep. blocks 0..127: x -> xhi/xlo (hi/lo bf16 split) and Xt
// (transposed bf16 [256][8192], for the PV B-operand). blocks 128..135:
// Wq/Wk -> hi/lo bf16.
// ---------------------------------------------------------------------------
__global__ __launch_bounds__(256) void prep_kernel(
    const float* __restrict__ x, const float* __restrict__ Wq, const float* __restrict__ Wk,
    unsigned short* __restrict__ xhi, unsigned short* __restrict__ xlo,
    unsigned short* __restrict__ Xt,
    unsigned short* __restrict__ Wqh, unsigned short* __restrict__ Wql,
    unsigned short* __restrict__ Wkh, unsigned short* __restrict__ Wkl)
{
    __shared__ unsigned short tile[64 * 256];   // swizzled [c][f] bf16
    int b = blockIdx.x, t = threadIdx.x;
    if (b < 128) {
        int rowbase = b * 64;
        int c = t >> 2, f0 = (t & 3) * 64;
        const float* xp = x + (size_t)(rowbase + c) * D_DIM + f0;
        size_t gbase = (size_t)(rowbase + c) * D_DIM + f0;
#pragma unroll
        for (int i = 0; i < 8; ++i) {
            float4 a4 = *(const float4*)(xp + 8 * i);
            float4 b4 = *(const float4*)(xp + 8 * i + 4);
            float v[8] = {a4.x, a4.y, a4.z, a4.w, b4.x, b4.y, b4.z, b4.w};
            bf16x8 hv, lv;
#pragma unroll
            for (int j = 0; j < 8; ++j) {
                unsigned short h = f2bf(v[j]);
                hv[j] = (short)h;
                lv[j] = (short)f2bf(v[j] - bf2f(h));
            }
            *(bf16x8*)(xhi + gbase + 8 * i) = hv;
            *(bf16x8*)(xlo + gbase + 8 * i) = lv;
            // swizzled LDS stage: element f at tile[c*256 + (f ^ ((c&7)<<3))]
            *(bf16x8*)(&tile[c * 256 + (((f0 + 8 * i) ^ ((c & 7) << 3)))]) = hv;
        }
        __syncthreads();
        int f = t;
        unsigned short vals[64];
#pragma unroll
        for (int c2 = 0; c2 < 64; ++c2)
            vals[c2] = tile[c2 * 256 + (f ^ ((c2 & 7) << 3))];
#pragma unroll
        for (int i = 0; i < 8; ++i) {
            bf16x8 pv;
#pragma unroll
            for (int j = 0; j < 8; ++j) pv[j] = (short)vals[8 * i + j];
            *(bf16x8*)(Xt + (size_t)f * N_ROWS + rowbase + 8 * i) = pv;
        }
    } else {
        int wb = b - 128;
        const float* src = (wb < 4) ? Wq : Wk;
        unsigned short* dh = (wb < 4) ? Wqh : Wkh;
        unsigned short* dl = (wb < 4) ? Wql : Wkl;
        int base = (wb & 3) * 16384;
#pragma unroll 4
        for (int i = 0; i < 64; ++i) {
            int idx = base + i * 256 + t;
            float v = src[idx];
            unsigned short h = f2bf(v);
            dh[idx] = h;
            dl[idx] = f2bf(v - bf2f(h));
        }
    }
}

// ---------------------------------------------------------------------------
// Kernel 1: y = x@W^T + b via split-bf16 MFMA (fp32-accurate), then Lorentz
// transform. Stores Qb bf16 (col 0 zeroed -> MFMA later gives spatial-only
// dot) and q0 (time) f32. One wave per 16 rows.
// ---------------------------------------------------------------------------
__global__ __launch_bounds__(64) void qk_kernel(
    const unsigned short* __restrict__ xhi, const unsigned short* __restrict__ xlo,
    const unsigned short* __restrict__ Wh, const unsigned short* __restrict__ Wl,
    const float* __restrict__ bias, const float* __restrict__ logscale,
    unsigned short* __restrict__ Qb, float* __restrict__ q0)
{
    int lane = threadIdx.x;
    int rowb = blockIdx.x * 16;
    int m = lane & 15, g = lane >> 4;

    bf16x8 ah[8], al[8];
    size_t abase = (size_t)(rowb + m) * D_DIM + g * 8;
#pragma unroll
    for (int k = 0; k < 8; ++k) {
        ah[k] = *(const bf16x8*)(xhi + abase + k * 32);
        al[k] = *(const bf16x8*)(xlo + abase + k * 32);
    }
    f32x4 acc[16];
#pragma unroll
    for (int fn = 0; fn < 16; ++fn) {
        f32x4 a = (f32x4){0.f, 0.f, 0.f, 0.f};
        size_t wbase = (size_t)(fn * 16 + m) * D_DIM + g * 8;
#pragma unroll
        for (int k = 0; k < 8; ++k) {
            bf16x8 bh = *(const bf16x8*)(Wh + wbase + k * 32);
            bf16x8 bl = *(const bf16x8*)(Wl + wbase + k * 32);
            a = mfma16(ah[k], bh, a);
            a = mfma16(ah[k], bl, a);
            a = mfma16(al[k], bh, a);
        }
        acc[fn] = a;
    }
    float es = expf(logscale[0]);
#pragma unroll
    for (int fn = 0; fn < 16; ++fn) {
        float bv = bias[fn * 16 + m];
#pragma unroll
        for (int r = 0; r < 4; ++r) acc[fn][r] += bv;
    }
#pragma unroll
    for (int r = 0; r < 4; ++r) {
        float p = 0.f;
#pragma unroll
        for (int fn = 0; fn < 16; ++fn) { float v = acc[fn][r]; p += v * v; }
        if (m == 0) p -= acc[0][r] * acc[0][r];   // exclude col 0 (time input)
        p += __shfl_xor(p, 1);
        p += __shfl_xor(p, 2);
        p += __shfl_xor(p, 4);
        p += __shfl_xor(p, 8);
        float y0 = __shfl(acc[0][r], g * 16);     // col-0 value for this row
        float tt = es / (1.f + expf(-y0)) + 1.1f; // sigmoid(y0)*exp(ls)+1.1
        float ssq = fmaxf(p, 1e-8f);
        float s = sqrtf((tt * tt - 1.f) / ssq);
        int row = rowb + g * 4 + r;
#pragma unroll
        for (int fn = 0; fn < 16; ++fn) {
            float v = acc[fn][r] * s;
            Qb[(size_t)row * D_DIM + fn * 16 + m] =
                (fn == 0 && m == 0) ? (unsigned short)0 : f2bf(v);
        }
        if (m == 0) q0[row] = tt;
    }
}

// ---------------------------------------------------------------------------
// Kernel 2: fused cin -> sigmoid -> att store + support accumulation.
// Grid (64 row-blocks of 128) x (nchunk col-chunks). 8 waves (2m x 2n),
// 64-col strips. LDS: Ks[64][256] (att_lds aliases its first 16KB),
// Xs[256][64] transposed x. All LDS XOR-swizzled (T2-style).
// ---------------------------------------------------------------------------
__global__ __launch_bounds__(512, 2) void att_kernel(
    const unsigned short* __restrict__ Qb, const unsigned short* __restrict__ Kb,
    const float* __restrict__ q0, const float* __restrict__ k0,
    const unsigned short* __restrict__ Xt,
    const float* __restrict__ p_scale, const float* __restrict__ p_bias,
    float* __restrict__ att_out, float* __restrict__ partial, int chunkW)
{
    __shared__ unsigned short Ks[64 * 256];  // 32KB; first 16KB reused as att_lds
    __shared__ unsigned short Xs[256 * 64];  // 32KB
    int tid = threadIdx.x;
    int lane = tid & 63, wid = tid >> 6;
    int wm = wid >> 1, wn = wid & 1;
    int m16 = lane & 15, g = lane >> 4;
    int rowbase = blockIdx.x * 128;
    int colbase = blockIdx.y * chunkW;
    float as = p_scale[0], ab = p_bias[0];

    // hoist Q fragments (A-operand) and q0 for this wave's 32 rows
    bf16x8 qa[2][8];
#pragma unroll
    for (int mi = 0; mi < 2; ++mi) {
        size_t base = (size_t)(rowbase + wm * 32 + mi * 16 + m16) * D_DIM + g * 8;
#pragma unroll
        for (int k = 0; k < 8; ++k)
            qa[mi][k] = *(const bf16x8*)(Qb + base + k * 32);
    }
    float q0v[2][4];
#pragma unroll
    for (int mi = 0; mi < 2; ++mi)
#pragma unroll
        for (int r = 0; r < 4; ++r)
            q0v[mi][r] = q0[rowbase + wm * 32 + mi * 16 + g * 4 + r];

    f32x4 oacc[2][8];
#pragma unroll
    for (int mi = 0; mi < 2; ++mi)
#pragma unroll
        for (int n = 0; n < 8; ++n)
            oacc[mi][n] = (f32x4){0.f, 0.f, 0.f, 0.f};

    int nstrips = chunkW / 64;
    int sc = tid >> 3, sko = (tid & 7) * 32;   // K staging: 64B per thread
    int sf = tid >> 1, sco = (tid & 1) * 32;   // Xt staging: 64B per thread

    for (int s = 0; s < nstrips; ++s) {
        int cb = colbase + s * 64;
        if (s) __syncthreads();                 // prev PV done with att_lds/Xs
        {
            const unsigned short* srcK = Kb + (size_t)(cb + sc) * D_DIM + sko;
            unsigned short* dK = Ks + sc * 256;
            int swK = (sc & 7) << 3;
#pragma unroll
            for (int i = 0; i < 4; ++i)
                *(bf16x8*)(dK + ((sko + 8 * i) ^ swK)) = *(const bf16x8*)(srcK + 8 * i);
            const unsigned short* srcX = Xt + (size_t)sf * N_ROWS + cb + sco;
            unsigned short* dX = Xs + sf * 64;
            int swX = (sf & 7) << 3;
#pragma unroll
            for (int i = 0; i < 4; ++i)
                *(bf16x8*)(dX + ((sco + 8 * i) ^ swX)) = *(const bf16x8*)(srcX + 8 * i);
        }
        __syncthreads();                        // tiles staged

        // S = Q_spatial . K_spatial^T  (128x64 per block, 32x32 per wave)
        f32x4 sacc[2][2];
#pragma unroll
        for (int mi = 0; mi < 2; ++mi)
#pragma unroll
            for (int fn = 0; fn < 2; ++fn)
                sacc[mi][fn] = (f32x4){0.f, 0.f, 0.f, 0.f};
#pragma unroll
        for (int k = 0; k < 8; ++k) {
            bf16x8 bk[2];
#pragma unroll
            for (int fn = 0; fn < 2; ++fn) {
                int row = wn * 32 + fn * 16 + m16;
                bk[fn] = *(const bf16x8*)(Ks + row * 256 + (((k * 32 + g * 8)) ^ ((row & 7) << 3)));
            }
#pragma unroll
            for (int mi = 0; mi < 2; ++mi)
#pragma unroll
                for (int fn = 0; fn < 2; ++fn)
                    sacc[mi][fn] = mfma16(qa[mi][k], bk[fn], sacc[mi][fn]);
        }
        __syncthreads();                        // all K reads done (alias safe)

        // epilogue: cin -> sigmoid; store f32 att; stage bf16 att into LDS
        float k0v[2];
#pragma unroll
        for (int fn = 0; fn < 2; ++fn)
            k0v[fn] = k0[cb + wn * 32 + fn * 16 + m16];
        unsigned short* As = Ks;                // alias: att[128][64] bf16
#pragma unroll
        for (int mi = 0; mi < 2; ++mi)
#pragma unroll
            for (int fn = 0; fn < 2; ++fn)
#pragma unroll
                for (int r = 0; r < 4; ++r) {
                    float cin = sacc[mi][fn][r] - q0v[mi][r] * k0v[fn];
                    float z = (2.f + 2.f * cin) / as + ab;
                    float attv = 1.f / (1.f + expf(-z));
                    int row = wm * 32 + mi * 16 + g * 4 + r;
                    int col = wn * 32 + fn * 16 + m16;
                    att_out[(size_t)(rowbase + row) * N_ROWS + cb + col] = attv;
                    As[row * 64 + (col ^ ((row & 7) << 3))] = f2bf(attv);
                }
        __syncthreads();                        // att_lds visible

        // PV: O[128][256] += att[128][64] @ X[64][256]
#pragma unroll
        for (int kf = 0; kf < 2; ++kf) {
            bf16x8 pa[2];
#pragma unroll
            for (int mi = 0; mi < 2; ++mi) {
                int row = wm * 32 + mi * 16 + m16;
                pa[mi] = *(const bf16x8*)(As + row * 64 + (((kf * 32 + g * 8)) ^ ((row & 7) << 3)));
            }
#pragma unroll
            for (int n = 0; n < 8; ++n) {
                int f = wn * 128 + n * 16 + m16;
                bf16x8 xb = *(const bf16x8*)(Xs + f * 64 + (((kf * 32 + g * 8)) ^ ((f & 7) << 3)));
#pragma unroll
                for (int mi = 0; mi < 2; ++mi)
                    oacc[mi][n] = mfma16(pa[mi], xb, oacc[mi][n]);
            }
        }
    }

    // write partial support for this col-chunk
    float* pbase = partial + (size_t)blockIdx.y * N_ROWS * D_DIM;
#pragma unroll
    for (int mi = 0; mi < 2; ++mi)
#pragma unroll
        for (int n = 0; n < 8; ++n)
#pragma unroll
            for (int r = 0; r < 4; ++r) {
                int row = rowbase + wm * 32 + mi * 16 + g * 4 + r;
                int f = wn * 128 + n * 16 + m16;
                pbase[(size_t)row * D_DIM + f] = oacc[mi][n][r];
            }
}

// ---------------------------------------------------------------------------
// Kernel 3: reduce partials + Lorentz normalize. One wave per row.
// ---------------------------------------------------------------------------
__global__ __launch_bounds__(64) void norm_kernel(
    const float* __restrict__ partial, float* __restrict__ outp, int nchunk)
{
    int row = blockIdx.x, lane = threadIdx.x;
    float a0 = 0.f, a1 = 0.f, a2 = 0.f, a3 = 0.f;
    for (int p = 0; p < nchunk; ++p) {
        const float4 v = *(const float4*)(partial + ((size_t)p * N_ROWS + row) * D_DIM + lane * 4);
        a0 += v.x; a1 += v.y; a2 += v.z; a3 += v.w;
    }
    float sq = a0 * a0 + a1 * a1 + a2 * a2 + a3 * a3;
#pragma unroll
    for (int off = 1; off < 64; off <<= 1) sq += __shfl_xor(sq, off);
    float s0 = __shfl(a0, 0);                     // support[:,0]
    float neg = 2.f * s0 * s0 - sq;               // s0^2 - (sum - s0^2)
    float dn = sqrtf(fmaxf(fabsf(neg), 1e-8f));
    float inv = 1.f / dn;
    float4 o;
    o.x = a0 * inv; o.y = a1 * inv; o.z = a2 * inv; o.w = a3 * inv;
    *(float4*)(outp + (size_t)row * D_DIM + lane * 4) = o;
}

// ---------------------------------------------------------------------------
extern "C" void kernel_launch(void* const* d_in, const int* in_sizes, int n_in,
                              void* d_out, int out_size, void* d_ws, size_t ws_size,
                              hipStream_t stream)
{
    const float* x         = (const float*)d_in[0];
    const float* Wq        = (const float*)d_in[1];
    const float* bq        = (const float*)d_in[2];
    const float* sq_log    = (const float*)d_in[3];
    const float* Wk        = (const float*)d_in[4];
    const float* bk        = (const float*)d_in[5];
    const float* sk_log    = (const float*)d_in[6];
    const float* att_bias  = (const float*)d_in[7];
    const float* att_scale = (const float*)d_in[8];
    float* outp    = (float*)d_out;
    float* att_out = outp + (size_t)N_ROWS * D_DIM;

    char* w = (char*)d_ws;
    size_t used = 0;
    auto alloc = [&](size_t bytes) -> char* {
        char* p = w + used;
        used += (bytes + 255) & ~(size_t)255;
        return p;
    };
    unsigned short* xhi = (unsigned short*)alloc((size_t)N_ROWS * D_DIM * 2);
    unsigned short* xlo = (unsigned short*)alloc((size_t)N_ROWS * D_DIM * 2);
    unsigned short* XtB = (unsigned short*)alloc((size_t)N_ROWS * D_DIM * 2);
    unsigned short* Wqh = (unsigned short*)alloc((size_t)65536 * 2);
    unsigned short* Wql = (unsigned short*)alloc((size_t)65536 * 2);
    unsigned short* Wkh = (unsigned short*)alloc((size_t)65536 * 2);
    unsigned short* Wkl = (unsigned short*)alloc((size_t)65536 * 2);
    unsigned short* QbB = (unsigned short*)alloc((size_t)N_ROWS * D_DIM * 2);
    unsigned short* KbB = (unsigned short*)alloc((size_t)N_ROWS * D_DIM * 2);
    float* q0v = (float*)alloc((size_t)N_ROWS * 4);
    float* k0v = (float*)alloc((size_t)N_ROWS * 4);

    int nchunk = 4;
    while (nchunk > 1 &&
           used + (size_t)nchunk * N_ROWS * D_DIM * 4 > ws_size)
        nchunk >>= 1;
    float* partial = (float*)alloc((size_t)nchunk * N_ROWS * D_DIM * 4);

    hipLaunchKernelGGL(prep_kernel, dim3(136), dim3(256), 0, stream,
                       x, Wq, Wk, xhi, xlo, XtB, Wqh, Wql, Wkh, Wkl);
    hipLaunchKernelGGL(qk_kernel, dim3(N_ROWS / 16), dim3(64), 0, stream,
                       xhi, xlo, Wqh, Wql, bq, sq_log, QbB, q0v);
    hipLaunchKernelGGL(qk_kernel, dim3(N_ROWS / 16), dim3(64), 0, stream,
                       xhi, xlo, Wkh, Wkl, bk, sk_log, KbB, k0v);
    int chunkW = N_ROWS / nchunk;
    hipLaunchKernelGGL(att_kernel, dim3(N_ROWS / 128, nchunk), dim3(512), 0, stream,
                       QbB, KbB, q0v, k0v, XtB, att_scale, att_bias,
                       att_out, partial, chunkW);
    hipLaunchKernelGGL(norm_kernel, dim3(N_ROWS), dim3(64), 0, stream,
                       partial, outp, nchunk);
}